// Round 2
// baseline (58.661 us; speedup 1.0000x reference)
//
#include <hip/hip_runtime.h>
#include <hip/hip_bf16.h>

typedef float f32x4 __attribute__((ext_vector_type(4)));
typedef short short8 __attribute__((ext_vector_type(8)));

constexpr int TOKENS = 16;
constexpr int IN_F   = 4096;
constexpr int OUT_F  = 11008;
constexpr int NTILES = OUT_F / 16;   // 688 tiles -> 4 single-wave blocks each? no: 1 wave per tile

// f32 -> bf16 round-to-nearest-even
__device__ __forceinline__ unsigned short bf16_rne(float f) {
    unsigned u = __builtin_bit_cast(unsigned, f);
    u += 0x7fffu + ((u >> 16) & 1u);
    return (unsigned short)(u >> 16);
}
// int (0..126) -> bf16 exact (<= 7 significant bits)
__device__ __forceinline__ short bf16_from_int(int v) {
    float f = (float)v;
    return (short)(__builtin_bit_cast(unsigned, f) >> 16);
}

// Pre-pass: convert x (16x4096 f32) to bf16 once into workspace.
__global__ __launch_bounds__(256) void cvt_x_kernel(
    const float* __restrict__ x, unsigned short* __restrict__ xb)
{
    const int i = (blockIdx.x * 256 + threadIdx.x) * 4;
    float4 v = *(const float4*)(x + i);
    ushort4 o;
    o.x = bf16_rne(v.x); o.y = bf16_rne(v.y);
    o.z = bf16_rne(v.z); o.w = bf16_rne(v.w);
    *(ushort4*)(xb + i) = o;
}

// One wave per 16-column output tile, full K=4096 per wave.
// No LDS, no barriers. Grid = 688 blocks x 64 threads.
__global__ __launch_bounds__(64) void Int8Linear_kernel(
    const unsigned short* __restrict__ xb,  // [16][4096] bf16
    const int*   __restrict__ w,            // [11008][4096] int32 (0..126)
    const float* __restrict__ scale,        // [11008]
    const float* __restrict__ bias,         // [11008]
    float*       __restrict__ out)          // [16][11008] f32
{
    const int lane = threadIdx.x;           // 0..63
    const int m    = lane & 15;             // token row (A) / output col (B)
    const int g    = lane >> 4;             // k-group (0..3), 8 elems each
    const int n0   = blockIdx.x * 16;

    const unsigned short* xp = xb + (size_t)m * IN_F + g * 8;
    const int*            wp = w  + (size_t)(n0 + m) * IN_F + g * 8;

    f32x4 acc = {0.f, 0.f, 0.f, 0.f};

    #pragma unroll 8
    for (int kb = 0; kb < IN_F / 32; ++kb) {
        short8 a = *(const short8*)xp;      // 8 bf16, 16B
        int4   wa = *(const int4*)wp;       // 4 int32
        int4   wb = *(const int4*)(wp + 4); // 4 int32
        xp += 32; wp += 32;

        short8 b;
        b[0] = bf16_from_int(wa.x); b[1] = bf16_from_int(wa.y);
        b[2] = bf16_from_int(wa.z); b[3] = bf16_from_int(wa.w);
        b[4] = bf16_from_int(wb.x); b[5] = bf16_from_int(wb.y);
        b[6] = bf16_from_int(wb.z); b[7] = bf16_from_int(wb.w);

        acc = __builtin_amdgcn_mfma_f32_16x16x32_bf16(a, b, acc, 0, 0, 0);
    }

    // C/D layout: col = lane&15 (output n), row = (lane>>4)*4 + r (token)
    const int o = n0 + m;
    const float sc = scale[o];
    const float bi = bias[o];
    #pragma unroll
    for (int r = 0; r < 4; ++r) {
        const int row = g * 4 + r;
        out[(size_t)row * OUT_F + o] = acc[r] * sc + bi;
    }
}

extern "C" void kernel_launch(void* const* d_in, const int* in_sizes, int n_in,
                              void* d_out, int out_size, void* d_ws, size_t ws_size,
                              hipStream_t stream) {
    const float* x     = (const float*)d_in[0];
    const int*   w     = (const int*)d_in[1];
    const float* scale = (const float*)d_in[2];
    const float* bias  = (const float*)d_in[3];
    float*       out   = (float*)d_out;
    unsigned short* xb = (unsigned short*)d_ws;   // 16*4096*2 = 128 KB

    // 16*4096 = 65536 elems / (256 threads * 4/thread) = 64 blocks
    cvt_x_kernel<<<64, 256, 0, stream>>>(x, xb);
    Int8Linear_kernel<<<NTILES, 64, 0, stream>>>(xb, w, scale, bias, out);
}

// Round 3
// 44.306 us; speedup vs baseline: 1.3240x; 1.3240x over previous
//
#include <hip/hip_runtime.h>
#include <hip/hip_bf16.h>

typedef float f32x4 __attribute__((ext_vector_type(4)));
typedef short short8 __attribute__((ext_vector_type(8)));

constexpr int TOKENS = 16;
constexpr int IN_F   = 4096;
constexpr int OUT_F  = 11008;
constexpr int WAVES  = 4;              // K-split factor
constexpr int SEG_K  = IN_F / WAVES;   // 1024
constexpr int NTILES = OUT_F / 16;     // 688

// f32 -> bf16 round-to-nearest-even
__device__ __forceinline__ unsigned short bf16_rne(float f) {
    unsigned u = __builtin_bit_cast(unsigned, f);
    u += 0x7fffu + ((u >> 16) & 1u);
    return (unsigned short)(u >> 16);
}
// int (0..126) -> bf16 exact (<= 7 significant bits): truncation == RNE
__device__ __forceinline__ short bf16_from_int(int v) {
    float f = (float)v;
    return (short)(__builtin_bit_cast(unsigned, f) >> 16);
}

// Pre-pass: convert x (16x4096 f32) to bf16 once into workspace.
__global__ __launch_bounds__(256) void cvt_x_kernel(
    const float* __restrict__ x, unsigned short* __restrict__ xb)
{
    const int i = (blockIdx.x * 256 + threadIdx.x) * 4;
    float4 v = *(const float4*)(x + i);
    ushort4 o;
    o.x = bf16_rne(v.x); o.y = bf16_rne(v.y);
    o.z = bf16_rne(v.z); o.w = bf16_rne(v.w);
    *(ushort4*)(xb + i) = o;
}

// 688 blocks x 256 threads; 4 waves K-split SEG_K each; LDS reduce + epilogue.
__global__ __launch_bounds__(256, 4) void Int8Linear_kernel(
    const unsigned short* __restrict__ xb,  // [16][4096] bf16
    const int*   __restrict__ w,            // [11008][4096] int32 (0..126)
    const float* __restrict__ scale,        // [11008]
    const float* __restrict__ bias,         // [11008]
    float*       __restrict__ out)          // [16][11008] f32
{
    const int tid  = threadIdx.x;
    const int wave = tid >> 6;        // 0..3 -> K segment
    const int lane = tid & 63;
    const int m    = lane & 15;       // token row (A) / output col (B)
    const int g    = lane >> 4;       // k-group (0..3), 8 elems each
    const int n0   = blockIdx.x * 16;

    const unsigned short* xp = xb + (size_t)m * IN_F + wave * SEG_K + g * 8;
    const int*            wp = w  + (size_t)(n0 + m) * IN_F + wave * SEG_K + g * 8;

    f32x4 acc = {0.f, 0.f, 0.f, 0.f};

    #pragma unroll 8
    for (int kb = 0; kb < SEG_K / 32; ++kb) {
        short8 a  = *(const short8*)xp;     // 8 bf16 of x, 16B
        int4   wa = *(const int4*)wp;       // 4 int32 weights
        int4   wb = *(const int4*)(wp + 4); // 4 int32 weights
        xp += 32; wp += 32;

        short8 b;
        b[0] = bf16_from_int(wa.x); b[1] = bf16_from_int(wa.y);
        b[2] = bf16_from_int(wa.z); b[3] = bf16_from_int(wa.w);
        b[4] = bf16_from_int(wb.x); b[5] = bf16_from_int(wb.y);
        b[6] = bf16_from_int(wb.z); b[7] = bf16_from_int(wb.w);

        acc = __builtin_amdgcn_mfma_f32_16x16x32_bf16(a, b, acc, 0, 0, 0);
    }

    // Cross-wave K reduction in LDS, then fused scale+bias epilogue.
    __shared__ float red[WAVES][16][16];
    #pragma unroll
    for (int r = 0; r < 4; ++r)
        red[wave][g * 4 + r][m] = acc[r];   // row=(lane>>4)*4+r (token), col=lane&15
    __syncthreads();

    const int row = tid >> 4;   // token 0..15 (tid 0..255)
    const int col = tid & 15;
    float s = red[0][row][col] + red[1][row][col]
            + red[2][row][col] + red[3][row][col];
    const int o = n0 + col;
    out[(size_t)row * OUT_F + o] = s * scale[o] + bias[o];
}

extern "C" void kernel_launch(void* const* d_in, const int* in_sizes, int n_in,
                              void* d_out, int out_size, void* d_ws, size_t ws_size,
                              hipStream_t stream) {
    const float* x     = (const float*)d_in[0];
    const int*   w     = (const int*)d_in[1];
    const float* scale = (const float*)d_in[2];
    const float* bias  = (const float*)d_in[3];
    float*       out   = (float*)d_out;
    unsigned short* xb = (unsigned short*)d_ws;   // 16*4096*2 = 128 KB

    cvt_x_kernel<<<64, 256, 0, stream>>>(x, xb);
    Int8Linear_kernel<<<NTILES, 256, 0, stream>>>(xb, w, scale, bias, out);
}